// Round 1
// baseline (215.071 us; speedup 1.0000x reference)
//
#include <hip/hip_runtime.h>

#define HSZ 2048
#define NL  8

// One block (4 waves) per output element j.
// Wave w (w=0..3 -> gate i,f,g,o) computes gates[w] = dot(w_ih[row], in) +
// dot(w_hh[row], h0) + b_ih[row] + b_hh[row], row = w*H + j.
// Thread 0 then applies the LSTM cell elementwise math and writes out[j].
__global__ __launch_bounds__(256) void lstm_layer_kernel(
    const float* __restrict__ in,     // [H] layer input
    const float* __restrict__ w_ih,   // [4H, H]
    const float* __restrict__ w_hh,   // [4H, H]
    const float* __restrict__ b_ih,   // [4H]
    const float* __restrict__ b_hh,   // [4H]
    const float* __restrict__ h0,     // [H]
    const float* __restrict__ c0,     // [H]
    float* __restrict__ out,          // [H]
    int apply_tanh)
{
    const int j    = blockIdx.x;           // 0..H-1
    const int wave = threadIdx.x >> 6;     // 0..3 == gate index
    const int lane = threadIdx.x & 63;
    const int row  = wave * HSZ + j;

    const float4* __restrict__ wih4 = (const float4*)(w_ih + (size_t)row * HSZ);
    const float4* __restrict__ whh4 = (const float4*)(w_hh + (size_t)row * HSZ);
    const float4* __restrict__ in4  = (const float4*)in;
    const float4* __restrict__ h04  = (const float4*)h0;

    float acc = 0.f;
    // 2048 floats = 512 float4 per row; 64 lanes -> 8 float4 per lane per row
    #pragma unroll
    for (int it = 0; it < 8; ++it) {
        const int k = it * 64 + lane;
        float4 a  = wih4[k];
        float4 b  = whh4[k];
        float4 xv = in4[k];
        float4 hv = h04[k];
        acc += a.x * xv.x + a.y * xv.y + a.z * xv.z + a.w * xv.w;
        acc += b.x * hv.x + b.y * hv.y + b.z * hv.z + b.w * hv.w;
    }

    // wave (64-lane) reduction
    #pragma unroll
    for (int off = 32; off > 0; off >>= 1)
        acc += __shfl_down(acc, off, 64);

    __shared__ float gates[4];
    if (lane == 0) gates[wave] = acc + b_ih[row] + b_hh[row];
    __syncthreads();

    if (threadIdx.x == 0) {
        const float gi = gates[0];
        const float gf = gates[1];
        const float gg = gates[2];
        const float go = gates[3];
        const float si = 1.f / (1.f + __expf(-gi));
        const float sf = 1.f / (1.f + __expf(-gf));
        const float so = 1.f / (1.f + __expf(-go));
        const float tg = tanhf(gg);
        float c_new = sf * c0[j] + si * tg;
        float h     = so * tanhf(c_new);
        if (apply_tanh) h = tanhf(h);
        out[j] = h;
    }
}

extern "C" void kernel_launch(void* const* d_in, const int* in_sizes, int n_in,
                              void* d_out, int out_size, void* d_ws, size_t ws_size,
                              hipStream_t stream) {
    const float* x    = (const float*)d_in[0];
    const float* w_ih = (const float*)d_in[1];  // [L, 4H, H]
    const float* w_hh = (const float*)d_in[2];  // [L, 4H, H]
    const float* b_ih = (const float*)d_in[3];  // [L, 4H]
    const float* b_hh = (const float*)d_in[4];  // [L, 4H]
    const float* h0   = (const float*)d_in[5];  // [L, 1, H]
    const float* c0   = (const float*)d_in[6];  // [L, 1, H]
    float* out  = (float*)d_out;                // [1,1,H] -> H floats
    float* buf0 = (float*)d_ws;
    float* buf1 = buf0 + HSZ;

    const float* cur = x;
    for (int l = 0; l < NL; ++l) {
        float* o = (l == NL - 1) ? out : ((l & 1) ? buf1 : buf0);
        lstm_layer_kernel<<<HSZ, 256, 0, stream>>>(
            cur,
            w_ih + (size_t)l * 4 * HSZ * HSZ,
            w_hh + (size_t)l * 4 * HSZ * HSZ,
            b_ih + (size_t)l * 4 * HSZ,
            b_hh + (size_t)l * 4 * HSZ,
            h0 + (size_t)l * HSZ,
            c0 + (size_t)l * HSZ,
            o,
            (l < NL - 1) ? 1 : 0);
        cur = o;
    }
}